// Round 4
// baseline (453.254 us; speedup 1.0000x reference)
//
#include <hip/hip_runtime.h>
#include <math.h>

#define BB 8
#define CC 1024
#define HH 56
#define WW 56
#define NB 256
#define NCLS 30
#define BC (BB * CC)                 // 8192 planes
#define PLANE (HH * WW)              // 3136
#define NWORD (NB / 2)               // 128 packed u16-pairs per column
#define CHW (HH * NWORD)             // 7168 packed colhist words (28 KB LDS)
#define NPART 16                     // partial global hists
#define NBLK 1024                    // mega grid: 4 blocks/CU exactly
#define NCHUNK 3136                  // 6,422,528 float4 / 2048
#define CHUNK_F4 2048                // 8 float4/thread per chunk

// two-level grid barrier: 16 padded group counters + 1 master per instance
#define BAR_GROUPS 16
#define BAR_STRIDE 16                // u32 padding (64 B) between counters
#define BAR_WORDS (BAR_STRIDE * (BAR_GROUPS + 1))  // 272 u32 per instance
#define NBAR 7
#define GRP_SZ (NBLK / BAR_GROUPS)   // 64 blocks per group

// ---------------------------------------------------------------------------
// Workspace layout (bytes):
//   colhist @ 0       : 57,344   u32[56][256]
//   gpart   @ 57,344  : 16,384   u32[16][256]
//   meta    @ 73,728  : flag u32[0], region int[1..3], bar @ u32[16..1935]
//   hist    @ 131,072 : 3,211,264  u32[3136][256]  (fallback only)
// total need = 3,342,336 B (observed ws = 411 MB)
// ---------------------------------------------------------------------------
#define META_U32 (16 + NBAR * BAR_WORDS)                 // 1920
#define ZERO_WORDS (HH * NB + NPART * NB + META_U32)     // 20352
#define HIST_OFF 131072ull

// ---------------------------------------------------------------------------
// Kernel 0: zero colhist + gpart + meta (contiguous 20,352 u32).
// Separate launch so the persistent kernel never races its own init.
// ---------------------------------------------------------------------------
__global__ void zero_kernel(unsigned* __restrict__ p) {
    const int i = blockIdx.x * 256 + threadIdx.x;  // grid 80*256 = 20480
    if (i < ZERO_WORDS) p[i] = 0u;
}

// ---------------------------------------------------------------------------
// Two-level software grid barrier (all NBLK blocks participate).
// Release/acquire via __threadfence (agent scope: cross-XCD L2 writeback/inv),
// arrivals via device-scope atomics — same structure as ROCm's grid.sync().
// ---------------------------------------------------------------------------
__device__ __forceinline__ void gsync(unsigned* bar_inst, int bid) {
    __syncthreads();
    __threadfence();  // release: prior global writes -> coherent point
    if (threadIdx.x == 0) {
        unsigned* lo = bar_inst + (bid & (BAR_GROUPS - 1)) * BAR_STRIDE;
        unsigned* hi = bar_inst + BAR_GROUPS * BAR_STRIDE;
        if (atomicAdd(lo, 1u) == GRP_SZ - 1u) atomicAdd(hi, 1u);
        while (__hip_atomic_load(hi, __ATOMIC_RELAXED,
                                 __HIP_MEMORY_SCOPE_AGENT) < BAR_GROUPS)
            __builtin_amdgcn_s_sleep(16);
    }
    __syncthreads();
    __threadfence();  // acquire: invalidate stale caches
}

// ---------------------------------------------------------------------------
// Wave / entropy helpers (identical reduction order to the verified kernels).
// ---------------------------------------------------------------------------
__device__ __forceinline__ float wave_sum(float v) {
#pragma unroll
    for (int off = 32; off > 0; off >>= 1) v += __shfl_xor(v, off);
    return v;
}

__device__ __forceinline__ float ilook(const unsigned* __restrict__ integ,
                                       int a, int b, int bin) {
    return (a == 0 || b == 0)
               ? 0.f
               : (float)integ[((size_t)((a - 1) * WW + (b - 1))) * NB + bin];
}

__device__ float region_ent(const unsigned* __restrict__ integ, int lane,
                            int xd, int ys, int yd) {
    float hb[4];
    float hs = 0.f;
#pragma unroll
    for (int k = 0; k < 4; k++) {
        const int bin = lane + 64 * k;
        const float hv = ilook(integ, xd, yd, bin) - ilook(integ, xd, ys, bin);
        hb[k] = hv;
        hs += hv;
    }
    hs = wave_sum(hs);
    float e = 0.f;
#pragma unroll
    for (int k = 0; k < 4; k++) {
        const float p = hb[k] / hs;
        e += p * log2f(p + 1e-9f);
    }
    return -wave_sum(e);
}

// ---------------------------------------------------------------------------
// The persistent kernel: 1024 blocks x 256 threads, all co-resident
// (4 blocks/CU: VGPR<=128 via launch_bounds, LDS 32KB*4 <= 160KB).
// Phases: ghist+colhist (LDS) -> flush -> B0 -> decide(blk0) -> B1 ->
//         [flag==2: full integral-hist EKLM, B2..B6] -> fused pool+FC (blk0..7)
// ---------------------------------------------------------------------------
__global__ __launch_bounds__(256, 4) void mega_kernel(
    const float* __restrict__ x, const float* __restrict__ wfc,
    unsigned* __restrict__ colhist, unsigned* __restrict__ gpart,
    unsigned* __restrict__ meta, unsigned* __restrict__ hist,
    float* __restrict__ out) {
    __shared__ unsigned smem[NB * 4 + CHW];  // 32 KB: lh[4][256] + ch[56][128]
    unsigned* lh = smem;
    unsigned* ch = smem + NB * 4;

    const int tid = threadIdx.x;
    const int bid = blockIdx.x;
    unsigned* flag = meta;
    int* region = (int*)(meta + 1);
    unsigned* bar = meta + 16;

    for (int i = tid; i < NB * 4 + CHW; i += 256) smem[i] = 0u;
    __syncthreads();

    // ---- phase 1: histogram into LDS (8 prefetched float4 per chunk) ----
    unsigned* wl = lh + ((tid >> 6) << 8);  // wave-private 256-bin hist
    for (int c = bid; c < NCHUNK; c += NBLK) {
        const float4* __restrict__ xb = (const float4*)x + (size_t)c * CHUNK_F4;
        float4 v[8];
#pragma unroll
        for (int it = 0; it < 8; ++it) v[it] = xb[it * 256 + tid];
#pragma unroll
        for (int it = 0; it < 8; ++it) {
            const int e0 = (c * CHUNK_F4 + it * 256 + tid) * 4;  // < 25.7M
            const int pl = e0 / PLANE;       // const-div -> magic mul
            const int li = e0 - pl * PLANE;  // plane-local, multiple of 4
            const bool r0 = (li < WW);       // whole float4 in row 0
            const float vv[4] = {v[it].x, v[it].y, v[it].z, v[it].w};
#pragma unroll
            for (int e = 0; e < 4; ++e) {
                const float f = vv[e];
                if (f >= 0.f && f <= 1.f) {      // histc: OOR dropped
                    int bin = (int)(f * 256.f);  // floor (f>=0)
                    if (bin > 255) bin = 255;    // v==1 -> last bin
                    atomicAdd(&wl[bin], 1u);
                    if (r0)                      // u16-packed col hist
                        atomicAdd(&ch[(li + e) * NWORD + (bin >> 1)],
                                  1u << ((bin & 1) << 4));
                }
            }
        }
    }
    __syncthreads();

    // ---- flush: gpart (16-way split) + colhist (sparse unpack) ----
    {
        const unsigned s =
            lh[tid] + lh[NB + tid] + lh[2 * NB + tid] + lh[3 * NB + tid];
        if (s) atomicAdd(&gpart[((bid & (NPART - 1)) << 8) + tid], s);
    }
    for (int i = tid; i < CHW; i += 256) {
        const unsigned w = ch[i];
        if (w) {
            const int col = i >> 7;
            const int b2 = (i & 127) << 1;
            const unsigned lo16 = w & 0xffffu, hi16 = w >> 16;
            if (lo16) atomicAdd(&colhist[col * NB + b2], lo16);
            if (hi16) atomicAdd(&colhist[col * NB + b2 + 1], hi16);
        }
    }
    gsync(bar + 0 * BAR_WORDS, bid);

    // ---- phase 2: decide (block 0; others wait at B1) ----
    float* ent_s = (float*)smem;  // lh/ch dead
    if (bid == 0) {
        const int lane = tid & 63;
        const int wv = tid >> 6;
        for (int w = wv; w < WW; w += 4) {
            float hb[4], hs = 0.f;
#pragma unroll
            for (int k = 0; k < 4; k++) {
                const int bin = lane + 64 * k;
                hb[k] = (float)colhist[w * NB + bin];
                hs += hb[k];
            }
            hs = wave_sum(hs);
            float e = 0.f;
#pragma unroll
            for (int k = 0; k < 4; k++) {
                const float p = hb[k] / hs;
                e += p * log2f(p + 1e-9f);
            }
            e = -wave_sum(e);
            if (lane == 0) ent_s[w] = e;
        }
        __syncthreads();
        if (tid < 64) {
            const int lane = tid;
            float best = -3.0e38f;
            int bestw = 0;
            for (int w = 0; w < WW; ++w) {
                const float e = ent_s[w];
                if (e > best) { best = e; bestw = w; }  // first max (argmax)
            }
            float hb[4], hs = 0.f;
#pragma unroll
            for (int k = 0; k < 4; k++) {
                const int bin = lane + 64 * k;
                unsigned t = 0;
#pragma unroll
                for (int p = 0; p < NPART; ++p) t += gpart[(p << 8) + bin];
                hb[k] = (float)t;
                hs += hb[k];
            }
            hs = wave_sum(hs);
            float e = 0.f;
#pragma unroll
            for (int k = 0; k < 4; k++) {
                const float p = hb[k] / hs;
                e += p * log2f(p + 1e-9f);
            }
            const float total_ent = -wave_sum(e);
            const float Ts0 = best / total_ent;  // cell ent == column ent
            if (lane == 0) {
                region[0] = 1;          // xd
                region[1] = bestw;      // ys
                region[2] = bestw + 1;  // yd
                *flag = (Ts0 >= 0.9f) ? 1u : 2u;
            }
        }
    }
    gsync(bar + 1 * BAR_WORDS, bid);

    const unsigned fl =
        __hip_atomic_load(flag, __ATOMIC_RELAXED, __HIP_MEMORY_SCOPE_AGENT);

    // ---- phase 3 (fallback only; bench data takes flag==1) ----
    if (fl != 1u) {
        const int gtid = bid * 256 + tid;
        // F0: zero per-cell hist
        for (int i = gtid; i < PLANE * NB; i += NBLK * 256) hist[i] = 0u;
        gsync(bar + 2 * BAR_WORDS, bid);
        // F1: accumulate per-cell hists (global atomics; perf-irrelevant path)
        for (int c = bid; c < NCHUNK; c += NBLK) {
            const float4* __restrict__ xb =
                (const float4*)x + (size_t)c * CHUNK_F4;
            for (int it = 0; it < 8; ++it) {
                const float4 v = xb[it * 256 + tid];
                const int e0 = (c * CHUNK_F4 + it * 256 + tid) * 4;
                const int pl = e0 / PLANE;
                const int li = e0 - pl * PLANE;  // cell index h*56+w
                const float vv[4] = {v.x, v.y, v.z, v.w};
                for (int e = 0; e < 4; ++e) {
                    const float f = vv[e];
                    if (f >= 0.f && f <= 1.f) {
                        int bin = (int)(f * 256.f);
                        if (bin > 255) bin = 255;
                        atomicAdd(&hist[(size_t)(li + e) * NB + bin], 1u);
                    }
                }
            }
        }
        gsync(bar + 3 * BAR_WORDS, bid);
        // F2: inclusive prefix along w (register-staged)
        if (gtid < HH * NB) {
            const int h = gtid >> 8, b = gtid & 255;
            unsigned* base = hist + (size_t)h * WW * NB + b;
            unsigned vreg[WW];
#pragma unroll
            for (int w = 0; w < WW; ++w) vreg[w] = base[(size_t)w * NB];
            unsigned cacc = 0;
#pragma unroll
            for (int w = 0; w < WW; ++w) {
                cacc += vreg[w];
                base[(size_t)w * NB] = cacc;
            }
        }
        gsync(bar + 4 * BAR_WORDS, bid);
        // F3: inclusive prefix along h
        if (gtid < WW * NB) {
            const int w = gtid >> 8, b = gtid & 255;
            unsigned* base = hist + (size_t)w * NB + b;
            unsigned vreg[HH];
#pragma unroll
            for (int h = 0; h < HH; ++h) vreg[h] = base[(size_t)h * WW * NB];
            unsigned cacc = 0;
#pragma unroll
            for (int h = 0; h < HH; ++h) {
                cacc += vreg[h];
                base[(size_t)h * WW * NB] = cacc;
            }
        }
        gsync(bar + 5 * BAR_WORDS, bid);
        // F4: greedy loop (block 0 wave 0), from fast-path region
        if (bid == 0 && tid < 64) {
            const int lane = tid;
            const float total_ent = region_ent(hist, lane, HH, 0, WW);
            int xd = region[0], ys = region[1], yd = region[2];
            float Ts = region_ent(hist, lane, xd, ys, yd) / total_ent;
            bool done = false;
            int iter = 0;
            while (Ts < 0.9f && !done && iter < 1000) {
                iter++;
                const float e_cur = region_ent(hist, lane, xd, ys, yd);
                const int ysm = (ys - 1 < 0) ? 0 : ys - 1;
                const int ydp = (yd + 1 > WW) ? WW : yd + 1;
                const bool c1 = (xd + 1 < HH) &&
                                (region_ent(hist, lane, xd + 1, ys, yd) > e_cur);
                const bool c2 = !c1 && (ys - 1 >= 0) &&
                                (region_ent(hist, lane, xd, ysm, yd) > e_cur);
                const bool c3 = !c1 && !c2 && (yd + 1 < WW) &&
                                (region_ent(hist, lane, xd, ys, ydp) > e_cur);
                if (c1) xd = xd + 1;
                else if (c2) ys = ys - 1;
                else if (c3) yd = yd + 1;
                done = !(c1 || c2 || c3);
                Ts = region_ent(hist, lane, xd, ys, yd) / total_ent;
            }
            if (lane == 0) {
                region[0] = xd;
                region[1] = ys;
                region[2] = yd;
            }
        }
        gsync(bar + 6 * BAR_WORDS, bid);
    }

    // ---- phase 4: fused pool + FC (blocks 0..7 = batch index) ----
    if (bid >= BB) return;
    const int xd = region[0], ys = region[1], yd = region[2];
    const int Wd = yd - ys;
    const int n = xd * Wd;
    const float area = fmaxf((float)n, 1.f);
    float* pl_s = (float*)smem;       // 1024 floats (reuse)
    float* red = (float*)smem + CC;   // 240 floats
    __syncthreads();
    const float* __restrict__ xb = x + (size_t)bid * CC * PLANE;
#pragma unroll
    for (int k = 0; k < 4; ++k) {
        const int c = tid + k * 256;
        const float* plane = xb + (size_t)c * PLANE;
        float s = 0.f;
        for (int j = 0; j < n; ++j) {
            const int r = j / Wd;
            const int cc2 = ys + (j - r * Wd);
            s += plane[r * WW + cc2];
        }
        pl_s[c] = s / area;
    }
    __syncthreads();
    if (tid < 240) {
        const int chunk = tid / NCLS;
        const int nn = tid - chunk * NCLS;
        const float* pv = pl_s + chunk * 128;
        const float* wv2 = wfc + (size_t)(chunk * 128) * NCLS + nn;
        float a0 = 0.f, a1 = 0.f, a2 = 0.f, a3 = 0.f;
        for (int c = 0; c < 128; c += 4) {
            a0 += pv[c + 0] * wv2[(c + 0) * NCLS];
            a1 += pv[c + 1] * wv2[(c + 1) * NCLS];
            a2 += pv[c + 2] * wv2[(c + 2) * NCLS];
            a3 += pv[c + 3] * wv2[(c + 3) * NCLS];
        }
        red[tid] = (a0 + a1) + (a2 + a3);
    }
    __syncthreads();
    if (tid < NCLS) {
        float s = 0.f;
#pragma unroll
        for (int ch2 = 0; ch2 < 8; ++ch2) s += red[ch2 * NCLS + tid];
        out[bid * NCLS + tid] = s;
    }
}

// ---------------------------------------------------------------------------
extern "C" void kernel_launch(void* const* d_in, const int* in_sizes, int n_in,
                              void* d_out, int out_size, void* d_ws, size_t ws_size,
                              hipStream_t stream) {
    const float* x = (const float*)d_in[0];    // [8,1024,56,56]
    const float* wfc = (const float*)d_in[1];  // [1024,30]
    float* out = (float*)d_out;                // [8,30]

    unsigned char* ws = (unsigned char*)d_ws;
    unsigned* colhist = (unsigned*)ws;                 // 57,344 B
    unsigned* gpart = (unsigned*)(ws + 57344);         // 16,384 B
    unsigned* meta = (unsigned*)(ws + 73728);          // 7,680 B
    unsigned* hist = (unsigned*)(ws + HIST_OFF);       // 3,211,264 B (fallback)

    zero_kernel<<<80, 256, 0, stream>>>(colhist);
    mega_kernel<<<NBLK, 256, 0, stream>>>(x, wfc, colhist, gpart, meta, hist,
                                          out);
}

// Round 5
// 177.883 us; speedup vs baseline: 2.5480x; 2.5480x over previous
//
#include <hip/hip_runtime.h>
#include <math.h>

#define BB 8
#define CC 1024
#define HH 56
#define WW 56
#define NB 256
#define NCLS 30
#define BC (BB * CC)                 // 8192 planes
#define PLANE (HH * WW)              // 3136
#define NPART 16                     // partial global hists
#define GH_BLOCKS 3136               // 6,422,528 float4 / 2048 per block
#define F4_PER_BLOCK 2048            // 8 float4/thread, register-prefetched
#define TB 64                        // tail grid: trivially co-resident

// ---------------------------------------------------------------------------
// Workspace layout (bytes):
//   colhist @ 0       : 57,344    u32[56][256]
//   gpart   @ 57,344  : 16,384    u32[16][256]
//   meta    @ 73,728  : 576       flag u32[0], region int[1..3], bar @ [16+i*16]
//   hist    @ 131,072 : 3,211,264 u32[3136][256]  (fallback only)
// ---------------------------------------------------------------------------
#define META_U32 144                                     // 16 + 8*16
#define ZERO_WORDS (HH * NB + NPART * NB + META_U32)     // 18,576
#define HIST_OFF 131072ull
#define FULL_NEED (HIST_OFF + (size_t)PLANE * NB * 4)    // 3,342,336

// ---------------------------------------------------------------------------
// Kernel 0: zero colhist + gpart + meta (contiguous 18,576 u32).
// ---------------------------------------------------------------------------
__global__ void zero_kernel(unsigned* __restrict__ p) {
    const int i = blockIdx.x * 256 + threadIdx.x;  // grid 73*256 = 18,688
    if (i < ZERO_WORDS) p[i] = 0u;
}

// ---------------------------------------------------------------------------
// Kernel 1: fused global 256-bin histogram + row-0 per-column histograms.
// VERBATIM the round-3 kernel (measured as part of the 169.8 us pipeline):
// 3136 blocks x 256 thr, 4 KB LDS, 8 prefetched float4/thread, wave-private
// LDS hist, row-0 quads (~2% of elements) add directly into the 57 KB
// L2-resident colhist, flush into gpart[bid&15] (196-deep atomic chains).
// ---------------------------------------------------------------------------
__global__ __launch_bounds__(256) void ghist_kernel(const float* __restrict__ x,
                                                    unsigned* __restrict__ colhist,
                                                    unsigned* __restrict__ gpart) {
    __shared__ unsigned lh[4 * NB];  // 4 KB
    const int tid = threadIdx.x;
    lh[tid] = 0u; lh[NB + tid] = 0u; lh[2 * NB + tid] = 0u; lh[3 * NB + tid] = 0u;
    __syncthreads();

    const size_t base_f4 = (size_t)blockIdx.x * F4_PER_BLOCK;
    const float4* __restrict__ xb = (const float4*)x + base_f4;
    float4 v[8];
#pragma unroll
    for (int it = 0; it < 8; ++it) v[it] = xb[it * 256 + tid];

    unsigned* wl = lh + ((tid >> 6) << 8);  // this wave's private hist
#pragma unroll
    for (int it = 0; it < 8; ++it) {
        const int j = it * 256 + tid;
        const int e0 = ((int)base_f4 + j) * 4;   // global element idx (<25.7M)
        const int pl = e0 / PLANE;               // const-div -> magic mul
        const int li = e0 - pl * PLANE;          // plane-local, multiple of 4
        const bool r0 = (li < WW);               // whole float4 is row 0
        const float vv[4] = {v[it].x, v[it].y, v[it].z, v[it].w};
#pragma unroll
        for (int e = 0; e < 4; ++e) {
            const float f = vv[e];
            if (f >= 0.f && f <= 1.f) {          // histc: OOR dropped
                int bin = (int)(f * 256.f);      // floor (f>=0)
                if (bin > 255) bin = 255;        // v==1 -> last bin
                atomicAdd(&wl[bin], 1u);
                if (r0) atomicAdd(&colhist[(li + e) * NB + bin], 1u);
            }
        }
    }
    __syncthreads();
    const unsigned s = lh[tid] + lh[NB + tid] + lh[2 * NB + tid] + lh[3 * NB + tid];
    if (s) atomicAdd(&gpart[((blockIdx.x & (NPART - 1)) << 8) + tid], s);
}

// ---------------------------------------------------------------------------
// Wave / entropy helpers (identical reduction order to the verified kernels).
// ---------------------------------------------------------------------------
__device__ __forceinline__ float wave_sum(float v) {
#pragma unroll
    for (int off = 32; off > 0; off >>= 1) v += __shfl_xor(v, off);
    return v;
}

__device__ __forceinline__ float ilook(const unsigned* __restrict__ integ,
                                       int a, int b, int bin) {
    return (a == 0 || b == 0)
               ? 0.f
               : (float)integ[((size_t)((a - 1) * WW + (b - 1))) * NB + bin];
}

__device__ float region_ent(const unsigned* __restrict__ integ, int lane,
                            int xd, int ys, int yd) {
    float hb[4];
    float hs = 0.f;
#pragma unroll
    for (int k = 0; k < 4; k++) {
        const int bin = lane + 64 * k;
        const float hv = ilook(integ, xd, yd, bin) - ilook(integ, xd, ys, bin);
        hb[k] = hv;
        hs += hv;
    }
    hs = wave_sum(hs);
    float e = 0.f;
#pragma unroll
    for (int k = 0; k < 4; k++) {
        const float p = hb[k] / hs;
        e += p * log2f(p + 1e-9f);
    }
    return -wave_sum(e);
}

// ---------------------------------------------------------------------------
// 64-block soft barrier. RMW-polled (atomicAdd(ctr,0) is always serviced at
// the device coherent point — never a stale local-L2 line, unlike a relaxed
// agent-scope load: round-4 lesson). 64 pollers at ~0.85us intervals is ~75
// RMW/us on one line — trivially serviced.
// ---------------------------------------------------------------------------
__device__ __forceinline__ void bsync(unsigned* __restrict__ ctr) {
    __syncthreads();
    if (threadIdx.x == 0) {
        __threadfence();                   // release
        atomicAdd(ctr, 1u);
        while (atomicAdd(ctr, 0u) < TB) __builtin_amdgcn_s_sleep(32);
    }
    __syncthreads();
    __threadfence();                       // acquire
}

// ---------------------------------------------------------------------------
// Kernel 2: tail — decide (block 0) -> barrier -> [flag==2: full fallback
// EKLM] -> fused pool+FC (blocks 0..7). 64 blocks x 256 threads.
// ---------------------------------------------------------------------------
__global__ __launch_bounds__(256) void tail_kernel(
    const float* __restrict__ x, const float* __restrict__ wfc,
    const unsigned* __restrict__ colhist, const unsigned* __restrict__ gpart,
    unsigned* __restrict__ meta, unsigned* __restrict__ hist,
    float* __restrict__ out, int have_hist) {
    __shared__ float shf[CC + 240];  // pl_s[1024] + red[240]; reused as ent_s
    __shared__ unsigned sfl;
    __shared__ int sreg[3];
    const int tid = threadIdx.x;
    const int bid = blockIdx.x;
    unsigned* flag = meta;
    int* region = (int*)(meta + 1);
    unsigned* bar = meta + 16;       // counters at bar[i*16], 64B apart

    // ---- decide (block 0 only; identical math to the verified rounds) ----
    if (bid == 0) {
        float* ent_s = shf;
        const int lane = tid & 63;
        const int wv = tid >> 6;
        for (int w = wv; w < WW; w += 4) {
            float hb[4], hs = 0.f;
#pragma unroll
            for (int k = 0; k < 4; k++) {
                const int bin = lane + 64 * k;
                hb[k] = (float)colhist[w * NB + bin];
                hs += hb[k];
            }
            hs = wave_sum(hs);
            float e = 0.f;
#pragma unroll
            for (int k = 0; k < 4; k++) {
                const float p = hb[k] / hs;
                e += p * log2f(p + 1e-9f);
            }
            e = -wave_sum(e);
            if (lane == 0) ent_s[w] = e;
        }
        __syncthreads();
        if (tid < 64) {
            const int ln = tid;
            float best = -3.0e38f;
            int bestw = 0;
            for (int w = 0; w < WW; ++w) {
                const float e = ent_s[w];
                if (e > best) { best = e; bestw = w; }  // first max (argmax)
            }
            float hb[4], hs = 0.f;
#pragma unroll
            for (int k = 0; k < 4; k++) {
                const int bin = ln + 64 * k;
                unsigned t = 0;
#pragma unroll
                for (int p = 0; p < NPART; ++p) t += gpart[(p << 8) + bin];
                hb[k] = (float)t;
                hs += hb[k];
            }
            hs = wave_sum(hs);
            float e = 0.f;
#pragma unroll
            for (int k = 0; k < 4; k++) {
                const float p = hb[k] / hs;
                e += p * log2f(p + 1e-9f);
            }
            const float total_ent = -wave_sum(e);
            const float Ts0 = best / total_ent;  // cell ent == column ent
            if (ln == 0) {
                region[0] = 1;          // xd
                region[1] = bestw;      // ys
                region[2] = bestw + 1;  // yd
                *flag = (Ts0 >= 0.9f) ? 1u : 2u;
            }
        }
    }
    bsync(&bar[0 * 16]);

    if (tid == 0) {
        sfl = atomicAdd(flag, 0u);
        sreg[0] = (int)atomicAdd((unsigned*)&region[0], 0u);
        sreg[1] = (int)atomicAdd((unsigned*)&region[1], 0u);
        sreg[2] = (int)atomicAdd((unsigned*)&region[2], 0u);
    }
    __syncthreads();

    // ---- fallback (never taken on bench data; correctness-only path) ----
    if (sfl != 1u && have_hist) {
        const int gtid = bid * 256 + tid;
        // F0: zero per-cell hist
        for (int i = gtid; i < PLANE * NB; i += TB * 256) hist[i] = 0u;
        bsync(&bar[1 * 16]);
        // F1: accumulate per-cell hists via global atomics
        for (int c = bid; c < GH_BLOCKS; c += TB) {
            const float4* __restrict__ xb = (const float4*)x + (size_t)c * F4_PER_BLOCK;
            for (int it = 0; it < 8; ++it) {
                const float4 v = xb[it * 256 + tid];
                const int e0 = (c * F4_PER_BLOCK + it * 256 + tid) * 4;
                const int pl = e0 / PLANE;
                const int li = e0 - pl * PLANE;  // cell index h*56+w
                const float vv[4] = {v.x, v.y, v.z, v.w};
                for (int e = 0; e < 4; ++e) {
                    const float f = vv[e];
                    if (f >= 0.f && f <= 1.f) {
                        int bin = (int)(f * 256.f);
                        if (bin > 255) bin = 255;
                        atomicAdd(&hist[(size_t)(li + e) * NB + bin], 1u);
                    }
                }
            }
        }
        bsync(&bar[2 * 16]);
        // F2: inclusive prefix along w (register-staged)
        if (gtid < HH * NB) {
            const int h = gtid >> 8, b = gtid & 255;
            unsigned* base = hist + (size_t)h * WW * NB + b;
            unsigned vreg[WW];
#pragma unroll
            for (int w = 0; w < WW; ++w) vreg[w] = base[(size_t)w * NB];
            unsigned cacc = 0;
#pragma unroll
            for (int w = 0; w < WW; ++w) { cacc += vreg[w]; base[(size_t)w * NB] = cacc; }
        }
        bsync(&bar[3 * 16]);
        // F3: inclusive prefix along h
        if (gtid < WW * NB) {
            const int w = gtid >> 8, b = gtid & 255;
            unsigned* base = hist + (size_t)w * NB + b;
            unsigned vreg[HH];
#pragma unroll
            for (int h = 0; h < HH; ++h) vreg[h] = base[(size_t)h * WW * NB];
            unsigned cacc = 0;
#pragma unroll
            for (int h = 0; h < HH; ++h) { cacc += vreg[h]; base[(size_t)h * WW * NB] = cacc; }
        }
        bsync(&bar[4 * 16]);
        // F4: greedy loop (block 0 wave 0), from fast-path region
        if (bid == 0 && tid < 64) {
            const int lane = tid;
            const float total_ent = region_ent(hist, lane, HH, 0, WW);
            int xd = region[0], ys = region[1], yd = region[2];
            float Ts = region_ent(hist, lane, xd, ys, yd) / total_ent;
            bool done = false;
            int iter = 0;
            while (Ts < 0.9f && !done && iter < 1000) {
                iter++;
                const float e_cur = region_ent(hist, lane, xd, ys, yd);
                const int ysm = (ys - 1 < 0) ? 0 : ys - 1;
                const int ydp = (yd + 1 > WW) ? WW : yd + 1;
                const bool c1 = (xd + 1 < HH) &&
                                (region_ent(hist, lane, xd + 1, ys, yd) > e_cur);
                const bool c2 = !c1 && (ys - 1 >= 0) &&
                                (region_ent(hist, lane, xd, ysm, yd) > e_cur);
                const bool c3 = !c1 && !c2 && (yd + 1 < WW) &&
                                (region_ent(hist, lane, xd, ys, ydp) > e_cur);
                if (c1) xd = xd + 1;
                else if (c2) ys = ys - 1;
                else if (c3) yd = yd + 1;
                done = !(c1 || c2 || c3);
                Ts = region_ent(hist, lane, xd, ys, yd) / total_ent;
            }
            if (lane == 0) { region[0] = xd; region[1] = ys; region[2] = yd; }
        }
        bsync(&bar[5 * 16]);
        if (tid == 0) {
            sreg[0] = (int)atomicAdd((unsigned*)&region[0], 0u);
            sreg[1] = (int)atomicAdd((unsigned*)&region[1], 0u);
            sreg[2] = (int)atomicAdd((unsigned*)&region[2], 0u);
        }
        __syncthreads();
    }

    // ---- fused pool + FC (blocks 0..7 = batch index) ----
    if (bid >= BB) return;
    const int xd = sreg[0], ys = sreg[1], yd = sreg[2];
    const int Wd = yd - ys;
    const int n = xd * Wd;
    const float area = fmaxf((float)n, 1.f);
    float* pl_s = shf;            // 1024 floats
    float* red = shf + CC;        // 240 floats
    __syncthreads();
    const float* __restrict__ xb = x + (size_t)bid * CC * PLANE;
#pragma unroll
    for (int k = 0; k < 4; ++k) {
        const int c = tid + k * 256;
        const float* plane = xb + (size_t)c * PLANE;
        float s = 0.f;
        for (int j = 0; j < n; ++j) {
            const int r = j / Wd;
            const int cc2 = ys + (j - r * Wd);
            s += plane[r * WW + cc2];
        }
        pl_s[c] = s / area;
    }
    __syncthreads();
    if (tid < 240) {
        const int chunk = tid / NCLS;
        const int nn = tid - chunk * NCLS;
        const float* pv = pl_s + chunk * 128;
        const float* wv2 = wfc + (size_t)(chunk * 128) * NCLS + nn;
        float a0 = 0.f, a1 = 0.f, a2 = 0.f, a3 = 0.f;
        for (int c = 0; c < 128; c += 4) {
            a0 += pv[c + 0] * wv2[(c + 0) * NCLS];
            a1 += pv[c + 1] * wv2[(c + 1) * NCLS];
            a2 += pv[c + 2] * wv2[(c + 2) * NCLS];
            a3 += pv[c + 3] * wv2[(c + 3) * NCLS];
        }
        red[tid] = (a0 + a1) + (a2 + a3);
    }
    __syncthreads();
    if (tid < NCLS) {
        float s = 0.f;
#pragma unroll
        for (int ch2 = 0; ch2 < 8; ++ch2) s += red[ch2 * NCLS + tid];
        out[bid * NCLS + tid] = s;
    }
}

// ---------------------------------------------------------------------------
extern "C" void kernel_launch(void* const* d_in, const int* in_sizes, int n_in,
                              void* d_out, int out_size, void* d_ws, size_t ws_size,
                              hipStream_t stream) {
    const float* x = (const float*)d_in[0];    // [8,1024,56,56]
    const float* wfc = (const float*)d_in[1];  // [1024,30]
    float* out = (float*)d_out;                // [8,30]

    unsigned char* ws = (unsigned char*)d_ws;
    unsigned* colhist = (unsigned*)ws;                 // 57,344 B
    unsigned* gpart = (unsigned*)(ws + 57344);         // 16,384 B
    unsigned* meta = (unsigned*)(ws + 73728);          // 576 B
    unsigned* hist = (unsigned*)(ws + HIST_OFF);       // 3,211,264 B (fallback)
    const int have_hist = (ws_size >= FULL_NEED) ? 1 : 0;

    zero_kernel<<<73, 256, 0, stream>>>(colhist);
    ghist_kernel<<<GH_BLOCKS, 256, 0, stream>>>(x, colhist, gpart);
    tail_kernel<<<TB, 256, 0, stream>>>(x, wfc, colhist, gpart, meta, hist,
                                        out, have_hist);
}